// Round 4
// baseline (261.557 us; speedup 1.0000x reference)
//
#include <hip/hip_runtime.h>

// Problem constants
#define BB      8
#define DIMD    1024
#define NTOK    4096
#define CC      6
#define TN      128           // n-columns per block tile (float4: 32 col-groups x 4)
#define NWAVE   8             // waves per block
#define NTHREADS (NWAVE * 64) // 512
#define RPW     (DIMD / NWAVE) // 128 d-rows per wave
#define ITERS   (RPW / 2)      // 64: each iter covers 2 d-rows (lane split)

__global__ __launch_bounds__(NTHREADS, 2)   // 1 block/CU (75 KB LDS), 8 waves
void lq_fused(const float* __restrict__ z,  const float* __restrict__ Wi,
              const float* __restrict__ bi, const float* __restrict__ Wo,
              const float* __restrict__ bo, float* __restrict__ out,
              float* __restrict__ idx_out,  float* __restrict__ loss_out)
{
    // per d-row 64B: {i0..3},{i4,i5,o0,o1},{o2..o5},{bo,-,-,-} -> ds_read_b128 x4, one base
    __shared__ float4 wt4[DIMD][4];  // 64 KB
    __shared__ float  acc[TN][15];   // 7.5 KB, stride 15 -> 4-way worst on fold atomics
    __shared__ float  qs[CC][TN];    // 3 KB
    __shared__ float  redA[2];
    __shared__ float  redw[NWAVE];

    const int t    = threadIdx.x;
    const int lane = t & 63;
    const int wv   = t >> 6;
    const int c    = lane & 31;     // column group (4 cols each)
    const int r    = lane >> 5;     // row parity within iter
    const int blk  = blockIdx.x;
    const int b    = blk >> 5;          // 32 n-tiles per batch
    const int n0   = (blk & 31) << 7;   // * TN

    // ---------------- stage weights to LDS (once per block) -----------------------
    for (int d = t; d < DIMD; d += NTHREADS) {
        const float* wr = Wo + d * CC;
        wt4[d][0] = make_float4(Wi[0*DIMD+d], Wi[1*DIMD+d], Wi[2*DIMD+d], Wi[3*DIMD+d]);
        wt4[d][1] = make_float4(Wi[4*DIMD+d], Wi[5*DIMD+d], wr[0], wr[1]);
        wt4[d][2] = make_float4(wr[2], wr[3], wr[4], wr[5]);
        wt4[d][3] = make_float4(bo[d], 0.f, 0.f, 0.f);
    }
    for (int i = t; i < TN * 15; i += NTHREADS) ((float*)acc)[i] = 0.f;
    __syncthreads();

    const int dbase = wv * RPW;
    const size_t zoff = ((size_t)b * DIMD + (size_t)(dbase + r)) * NTOK
                      + (size_t)n0 + (size_t)(c << 2);
    const float4* zp = (const float4*)(z + zoff);   // step 2 rows = 2*NTOK/4 float4s

    // ---------------- pass 1: x=Wi.z, y=Wo^T.z, bo.z, z.z for 4 columns ----------
    float xa[4][CC], ya[4][CC], zb4[4], zz4[4];
    #pragma unroll
    for (int j = 0; j < 4; ++j) {
        zb4[j] = 0.f; zz4[j] = 0.f;
        #pragma unroll
        for (int k = 0; k < CC; ++k) { xa[j][k] = 0.f; ya[j][k] = 0.f; }
    }

    #pragma unroll 2
    for (int i = 0; i < ITERS; ++i) {
        const float4 zv = zp[(size_t)i * (2 * NTOK / 4)];   // 1024B/wave-instr
        const int d = dbase + 2 * i + r;
        const float4 w0 = wt4[d][0];
        const float4 w1 = wt4[d][1];
        const float4 w2 = wt4[d][2];
        const float  bv = wt4[d][3].x;
        const float zj[4] = {zv.x, zv.y, zv.z, zv.w};
        #pragma unroll
        for (int j = 0; j < 4; ++j) {
            const float zvj = zj[j];
            xa[j][0] = fmaf(zvj, w0.x, xa[j][0]);
            xa[j][1] = fmaf(zvj, w0.y, xa[j][1]);
            xa[j][2] = fmaf(zvj, w0.z, xa[j][2]);
            xa[j][3] = fmaf(zvj, w0.w, xa[j][3]);
            xa[j][4] = fmaf(zvj, w1.x, xa[j][4]);
            xa[j][5] = fmaf(zvj, w1.y, xa[j][5]);
            ya[j][0] = fmaf(zvj, w1.z, ya[j][0]);
            ya[j][1] = fmaf(zvj, w1.w, ya[j][1]);
            ya[j][2] = fmaf(zvj, w2.x, ya[j][2]);
            ya[j][3] = fmaf(zvj, w2.y, ya[j][3]);
            ya[j][4] = fmaf(zvj, w2.z, ya[j][4]);
            ya[j][5] = fmaf(zvj, w2.w, ya[j][5]);
            zb4[j]   = fmaf(zvj, bv,   zb4[j]);
            zz4[j]   = fmaf(zvj, zvj,  zz4[j]);
        }
    }

    // fold row-parity halves (lane <-> lane+32), then cross-wave via LDS atomics
    #pragma unroll
    for (int j = 0; j < 4; ++j) {
        #pragma unroll
        for (int k = 0; k < CC; ++k) {
            xa[j][k] += __shfl_down(xa[j][k], 32);
            ya[j][k] += __shfl_down(ya[j][k], 32);
        }
        zb4[j] += __shfl_down(zb4[j], 32);
        zz4[j] += __shfl_down(zz4[j], 32);
    }
    if (r == 0) {
        #pragma unroll
        for (int j = 0; j < 4; ++j) {
            float* a = acc[(c << 2) + j];
            atomicAdd(&a[0],  xa[j][0]); atomicAdd(&a[1],  xa[j][1]);
            atomicAdd(&a[2],  xa[j][2]); atomicAdd(&a[3],  xa[j][3]);
            atomicAdd(&a[4],  xa[j][4]); atomicAdd(&a[5],  xa[j][5]);
            atomicAdd(&a[6],  ya[j][0]); atomicAdd(&a[7],  ya[j][1]);
            atomicAdd(&a[8],  ya[j][2]); atomicAdd(&a[9],  ya[j][3]);
            atomicAdd(&a[10], ya[j][4]); atomicAdd(&a[11], ya[j][5]);
            atomicAdd(&a[12], zb4[j]);   atomicAdd(&a[13], zz4[j]);
        }
    }
    __syncthreads();

    // ---------------- finalize + quantize (threads 0..127 = waves 0,1) ------------
    if (t < TN) {
        const float* pr = acc[t];
        float X0 = bi[0] + pr[0], X1 = bi[1] + pr[1], X2 = bi[2] + pr[2];
        float X3 = bi[3] + pr[3], X4 = bi[4] + pr[4], X5 = bi[5] + pr[5];
        float Y0 = pr[6], Y1 = pr[7], Y2 = pr[8], Y3 = pr[9], Y4 = pr[10], Y5 = pr[11];
        float ZB = pr[12], ZZ = pr[13];

        float idxf  = 0.f;
        float cross = ZB;
        float basis = 1.f;
        #define QSTEP(Xc, Yc, cidx)                                             \
        {                                                                       \
            float lv = rintf(fmaf((Xc), 8.f, 4.f));                             \
            lv = fminf(fmaxf(lv, 0.f), 7.f);                                    \
            float q = fmaf(lv, 0.125f, -0.5f);                                  \
            qs[cidx][t] = q;                                                    \
            cross = fmaf(q, (Yc), cross);                                       \
            idxf  = fmaf(lv, basis, idxf);                                      \
            basis *= 8.f;                                                       \
        }
        QSTEP(X0, Y0, 0) QSTEP(X1, Y1, 1) QSTEP(X2, Y2, 2)
        QSTEP(X3, Y3, 3) QSTEP(X4, Y4, 4) QSTEP(X5, Y5, 5)
        #undef QSTEP

        idx_out[b * NTOK + n0 + t] = idxf;        // integer-valued float, exact (< 2^24)
        float lossA = ZZ - 2.f * cross;           // sum z^2 - 2 sum out*z (this column)
        #pragma unroll
        for (int o = 32; o; o >>= 1) lossA += __shfl_down(lossA, o);
        if (lane == 0) redA[wv] = lossA;          // waves 0 and 1
    }
    __syncthreads();

    // ---------------- pass 2: out = Wo.q + bo, accumulate sum out^2 ----------------
    float q[CC][4];
    #pragma unroll
    for (int k = 0; k < CC; ++k)
        #pragma unroll
        for (int j = 0; j < 4; ++j) q[k][j] = qs[k][(c << 2) + j];

    float lossB = 0.f;
    float4* po = (float4*)(out + zoff);
    #pragma unroll 2
    for (int i = 0; i < ITERS; ++i) {
        const int d = dbase + 2 * i + r;
        const float4 w1 = wt4[d][1];
        const float4 w2 = wt4[d][2];
        const float  bv = wt4[d][3].x;
        float4 o4;
        float oj[4];
        #pragma unroll
        for (int j = 0; j < 4; ++j) {
            float o = bv;
            o = fmaf(q[0][j], w1.z, o);
            o = fmaf(q[1][j], w1.w, o);
            o = fmaf(q[2][j], w2.x, o);
            o = fmaf(q[3][j], w2.y, o);
            o = fmaf(q[4][j], w2.z, o);
            o = fmaf(q[5][j], w2.w, o);
            oj[j] = o;
            lossB = fmaf(o, o, lossB);
        }
        o4.x = oj[0]; o4.y = oj[1]; o4.z = oj[2]; o4.w = oj[3];
        po[(size_t)i * (2 * NTOK / 4)] = o4;       // 1024B/wave-instr
    }
    #pragma unroll
    for (int o = 32; o; o >>= 1) lossB += __shfl_down(lossB, o);
    if (lane == 0) redw[wv] = lossB;
    __syncthreads();

    if (t == 0) {
        float s = redA[0] + redA[1];
        #pragma unroll
        for (int w = 0; w < NWAVE; ++w) s += redw[w];
        atomicAdd(loss_out, s * (0.2f / 33554432.f));
    }
}

extern "C" void kernel_launch(void* const* d_in, const int* in_sizes, int n_in,
                              void* d_out, int out_size, void* d_ws, size_t ws_size,
                              hipStream_t stream) {
    const float* z  = (const float*)d_in[0];
    const float* Wi = (const float*)d_in[1];
    const float* bi = (const float*)d_in[2];
    const float* Wo = (const float*)d_in[3];
    const float* bo = (const float*)d_in[4];
    // d_in[5] = vals (uniform levels l/8 - 0.5) -- encoded analytically in the kernel

    float* out   = (float*)d_out;
    float* idxp  = out + (size_t)BB * DIMD * NTOK;   // 33554432
    float* lossp = idxp + (size_t)BB * NTOK;         // +32768

    // zero the loss accumulator (graph-capture-safe async memset on stream)
    hipMemsetAsync(lossp, 0, sizeof(float), stream);

    dim3 grid(BB * (NTOK / TN));   // 256 blocks = 1 per CU
    lq_fused<<<grid, NTHREADS, 0, stream>>>(z, Wi, bi, Wo, bo, out, idxp, lossp);
}